// Round 15
// baseline (86.712 us; speedup 1.0000x reference)
//
#include <hip/hip_runtime.h>
#include <float.h>

// Chamfer distance, B=16, N=2048, D=3, fp32 — MFMA, atomic-free.
// P_ij/2 = h_i + h_j - x_i.y_j  computed ENTIRELY inside one
// v_mfma_f32_32x32x16_bf16 via K-slot packing (C = 0):
//   k0-2:  (-xh).(yh)    k3-5: (-xl).(yh)   k6-8: (-xh).(yl)
//   k9,10: hx_hi*1 + hx_lo*1      k11,12: 1*hy_hi + 1*hy_lo
// (drops xl.yl and h lo-lo terms: total err ~3e-4 << 2.3e-3; the cross-term
// packing + C/D layout row=(r&3)+8(r>>2)+4(lane>>5), col=lane&31 are
// HW-proven by round 13's PASS.)
// r13 lesson: 2M contended inner-loop atomicMin = ~25 us of L2 serialization.
// Here: block = ALL 2048 i x 128 j -> col-mins are block-complete (plain
// store); row-mins are 16-way partials (plain store) + small combine kernel.

constexpr int B_ = 16;
constexpr int N_ = 2048;
constexpr int THREADS = 1024;
constexpr int WAVES = THREADS / 64;        // 16
constexpr int NJS = 16;                    // j-slice blocks per b
constexpr int JSL = N_ / NJS;              // 128 j per block
constexpr int JT = JSL / 32;               // 4 j-tiles
constexpr int ITPW = (N_ / 32) / WAVES;    // 4 i-tiles per wave

typedef float f32x16 __attribute__((ext_vector_type(16)));
typedef short s16x8  __attribute__((ext_vector_type(8)));

__device__ __forceinline__ unsigned short to_bf16(float f) {
    unsigned u = __float_as_uint(f);
    u += 0x7FFFu + ((u >> 16) & 1u);       // RNE
    return (unsigned short)(u >> 16);
}
__device__ __forceinline__ float from_bf16(unsigned short h) {
    return __uint_as_float(((unsigned)h) << 16);
}

// ws: float drow_part[NJS][B_][N_] (2 MiB), then float dcol[B_][N_] (128 KiB)
__global__ __launch_bounds__(THREADS, 4)
void cd_mfma_kernel(const float* __restrict__ x,
                    const float* __restrict__ y,
                    float* __restrict__ drow_part,
                    float* __restrict__ dcol) {
    const int js = blockIdx.x;
    const int b  = blockIdx.y;
    const int t  = (int)threadIdx.x;
    const int wv = t >> 6;
    const int lc = t & 31;
    const int hf = (t >> 5) & 1;

    constexpr unsigned short ONE = 0x3F80;  // bf16(1.0)

    __shared__ __align__(16) unsigned short ldsB[2][JSL][8];  // 4 KiB
    __shared__ float cmin[WAVES][JSL];                        // 8 KiB

    // ---- stage 128 y-points: pack both k-half B fragments ----
    if (t < JSL) {
        const float* yp = y + ((size_t)b * N_ + (size_t)js * JSL + t) * 3;
        const float f0 = yp[0], f1 = yp[1], f2 = yp[2];
        const unsigned short h0 = to_bf16(f0), h1 = to_bf16(f1), h2 = to_bf16(f2);
        const unsigned short l0 = to_bf16(f0 - from_bf16(h0));
        const unsigned short l1 = to_bf16(f1 - from_bf16(h1));
        const unsigned short l2 = to_bf16(f2 - from_bf16(h2));
        const float hy = 0.5f * (f0 * f0 + f1 * f1 + f2 * f2);
        const unsigned short hyh = to_bf16(hy);
        const unsigned short hyl = to_bf16(hy - from_bf16(hyh));
        unsigned short* p0 = &ldsB[0][t][0];
        p0[0] = h0; p0[1] = h1; p0[2] = h2;
        p0[3] = h0; p0[4] = h1; p0[5] = h2;
        p0[6] = l0; p0[7] = l1;
        unsigned short* p1 = &ldsB[1][t][0];
        p1[0] = l2; p1[1] = ONE; p1[2] = ONE;
        p1[3] = hyh; p1[4] = hyl;
        p1[5] = 0; p1[6] = 0; p1[7] = 0;
    }

    // ---- A fragments for this wave's 4 i-tiles ----
    s16x8 af[ITPW];
    #pragma unroll
    for (int k = 0; k < ITPW; ++k) {
        const int ig = wv * ITPW + k;                  // global i-tile
        const float* xp = x + ((size_t)b * N_ + (size_t)ig * 32 + lc) * 3;
        const float a0 = xp[0], a1 = xp[1], a2 = xp[2];
        const float n0 = -a0, n1 = -a1, n2 = -a2;
        const unsigned short xh0 = to_bf16(n0), xh1 = to_bf16(n1), xh2 = to_bf16(n2);
        const unsigned short xl0 = to_bf16(n0 - from_bf16(xh0));
        const unsigned short xl1 = to_bf16(n1 - from_bf16(xh1));
        const unsigned short xl2 = to_bf16(n2 - from_bf16(xh2));
        const float hx = 0.5f * (a0 * a0 + a1 * a1 + a2 * a2);
        const unsigned short hxh = to_bf16(hx);
        const unsigned short hxl = to_bf16(hx - from_bf16(hxh));
        s16x8 f;
        if (hf == 0) {
            f[0] = (short)xh0; f[1] = (short)xh1; f[2] = (short)xh2;
            f[3] = (short)xl0; f[4] = (short)xl1; f[5] = (short)xl2;
            f[6] = (short)xh0; f[7] = (short)xh1;
        } else {
            f[0] = (short)xh2; f[1] = (short)hxh; f[2] = (short)hxl;
            f[3] = (short)ONE; f[4] = (short)ONE;
            f[5] = 0; f[6] = 0; f[7] = 0;
        }
        af[k] = f;
    }
    __syncthreads();

    // ---- main: 4 i-tiles x 4 j-tiles, 1 MFMA each, C = 0 ----
    f32x16 zero;
    #pragma unroll
    for (int r = 0; r < 16; ++r) zero[r] = 0.0f;

    float colp[JT];
    #pragma unroll
    for (int jt = 0; jt < JT; ++jt) colp[jt] = FLT_MAX;

    #pragma unroll
    for (int k = 0; k < ITPW; ++k) {
        float runmin[16];
        #pragma unroll
        for (int r = 0; r < 16; ++r) runmin[r] = FLT_MAX;

        #pragma unroll
        for (int jt = 0; jt < JT; ++jt) {
            const s16x8 bf = *(const s16x8*)&ldsB[hf][jt * 32 + lc][0];
            const f32x16 acc =
                __builtin_amdgcn_mfma_f32_32x32x16_bf16(af[k], bf, zero, 0, 0, 0);
            #pragma unroll
            for (int r = 0; r < 16; ++r)
                runmin[r] = fminf(runmin[r], acc[r]);
            // col-min tree over this lane's 16 rows
            const float c0 = fminf(fminf(acc[0], acc[1]),  fminf(acc[2], acc[3]));
            const float c1 = fminf(fminf(acc[4], acc[5]),  fminf(acc[6], acc[7]));
            const float c2 = fminf(fminf(acc[8], acc[9]),  fminf(acc[10], acc[11]));
            const float c3 = fminf(fminf(acc[12], acc[13]), fminf(acc[14], acc[15]));
            colp[jt] = fminf(colp[jt], fminf(fminf(c0, c1), fminf(c2, c3)));
        }

        // row-min across the 32 col-lanes (stays within each 32-lane half)
        #pragma unroll
        for (int r = 0; r < 16; ++r) {
            float v = runmin[r];
            v = fminf(v, __shfl_xor(v, 1, 64));
            v = fminf(v, __shfl_xor(v, 2, 64));
            v = fminf(v, __shfl_xor(v, 4, 64));
            v = fminf(v, __shfl_xor(v, 8, 64));
            v = fminf(v, __shfl_xor(v, 16, 64));
            runmin[r] = v;
        }
        if (lc == 0) {
            float* base = drow_part + ((size_t)js * B_ + b) * N_
                        + (size_t)(wv * ITPW + k) * 32;
            #pragma unroll
            for (int r = 0; r < 16; ++r)
                base[(r & 3) + 8 * (r >> 2) + 4 * hf] = runmin[r];
        }
    }

    // ---- cols: combine halves, cross-wave via LDS, plain store ----
    #pragma unroll
    for (int jt = 0; jt < JT; ++jt) {
        float cw = colp[jt];
        cw = fminf(cw, __shfl_xor(cw, 32, 64));
        if (hf == 0) cmin[wv][jt * 32 + lc] = cw;
    }
    __syncthreads();
    if (t < JSL) {
        float m = cmin[0][t];
        #pragma unroll
        for (int w = 1; w < WAVES; ++w) m = fminf(m, cmin[w][t]);
        dcol[(size_t)b * N_ + (size_t)js * JSL + t] = m;
    }
}

// out[b] = (2/N) * (sum_i min_js drow_part[js][b][i] + sum_j dcol[b][j])
__global__ __launch_bounds__(THREADS)
void cd_sum_kernel(const float* __restrict__ drow_part,
                   const float* __restrict__ dcol,
                   float* __restrict__ out) {
    const int b = blockIdx.x;
    const int t = (int)threadIdx.x;

    float s = 0.0f;
    for (int i = t; i < N_; i += THREADS) {
        float m = drow_part[(size_t)b * N_ + i];
        #pragma unroll
        for (int js = 1; js < NJS; ++js)
            m = fminf(m, drow_part[((size_t)js * B_ + b) * N_ + i]);
        s += m;
    }
    for (int j = t; j < N_; j += THREADS)
        s += dcol[(size_t)b * N_ + j];

    #pragma unroll
    for (int o = 32; o > 0; o >>= 1)
        s += __shfl_down(s, o, 64);

    __shared__ float red[WAVES];
    if ((t & 63) == 0) red[t >> 6] = s;
    __syncthreads();
    if (t == 0) {
        float tot = 0.0f;
        #pragma unroll
        for (int w = 0; w < WAVES; ++w) tot += red[w];
        out[b] = tot * (2.0f / (float)N_);
    }
}

extern "C" void kernel_launch(void* const* d_in, const int* in_sizes, int n_in,
                              void* d_out, int out_size, void* d_ws, size_t ws_size,
                              hipStream_t stream) {
    const float* x = (const float*)d_in[0];
    const float* y = (const float*)d_in[1];
    float* out       = (float*)d_out;
    float* drow_part = (float*)d_ws;                       // 2 MiB
    float* dcol      = drow_part + (size_t)NJS * B_ * N_;  // 128 KiB

    cd_mfma_kernel<<<dim3(NJS, B_), dim3(THREADS), 0, stream>>>(
        x, y, drow_part, dcol);
    cd_sum_kernel<<<dim3(B_), dim3(THREADS), 0, stream>>>(
        drow_part, dcol, out);
}

// Round 16
// 32.967 us; speedup vs baseline: 2.6303x; 2.6303x over previous
//
#include <hip/hip_runtime.h>
#include <float.h>

// Chamfer distance, B=16, N=2048, D=3, fp32 — MFMA, atomic-free, spill-free.
// P_ij/2 = h_i + h_j - x_i.y_j computed ENTIRELY inside one
// v_mfma_f32_32x32x16_bf16 via K-slot packing (C = 0):
//   k0-2: (-xh).(yh)  k3-5: (-xl).(yh)  k6-8: (-xh).(yl)
//   k9,10: hx_hi*1 + hx_lo*1   k11,12: 1*hy_hi + 1*hy_lo
// (err ~3e-4 << 2.3e-3; packing + C/D layout HW-PROVEN by r13/r15 absmax=0.)
// r15 lesson (counters): VGPR=64 cap + 16-reg arrays -> 294 MB/dispatch of
// scratch traffic = 80 us. Fix: 256-thr blocks, no min-waves bound, one
// i-tile live at a time (~70 live regs), all arrays statically indexed.
// Block = 512 i x 256 j: row-mins block-complete over j -> drow_part[8][B][N];
// col-mins block-complete over i (LDS cross-wave) -> dcol_part[4][B][N].

constexpr int B_ = 16;
constexpr int N_ = 2048;
constexpr int THREADS = 256;
constexpr int WAVES = THREADS / 64;       // 4
constexpr int NJG = 8;                    // j-group blocks
constexpr int JSL = N_ / NJG;             // 256 j per block
constexpr int JT = JSL / 32;              // 8 j-tiles
constexpr int NIG = 4;                    // i-group blocks
constexpr int ISL = N_ / NIG;             // 512 i per block
constexpr int ITPW = ISL / 32 / WAVES;    // 4 i-tiles per wave

typedef float f32x16 __attribute__((ext_vector_type(16)));
typedef short s16x8  __attribute__((ext_vector_type(8)));

__device__ __forceinline__ unsigned short to_bf16(float f) {
    unsigned u = __float_as_uint(f);
    u += 0x7FFFu + ((u >> 16) & 1u);      // RNE
    return (unsigned short)(u >> 16);
}
__device__ __forceinline__ float from_bf16(unsigned short h) {
    return __uint_as_float(((unsigned)h) << 16);
}

// ws: float drow_part[NJG][B_][N_] (1 MiB), then float dcol_part[NIG][B_][N_] (512 KiB)
__global__ __launch_bounds__(THREADS)
void cd_mfma_kernel(const float* __restrict__ x,
                    const float* __restrict__ y,
                    float* __restrict__ drow_part,
                    float* __restrict__ dcol_part) {
    const int jg = blockIdx.x;            // 0..7
    const int ig = blockIdx.y;            // 0..3
    const int b  = blockIdx.z;            // 0..15
    const int t  = (int)threadIdx.x;
    const int wv = t >> 6;
    const int lc = t & 31;
    const int hf = (t >> 5) & 1;

    constexpr unsigned short ONE = 0x3F80;  // bf16(1.0)

    __shared__ __align__(16) unsigned short ldsB[2][JSL][8];  // 8 KiB
    __shared__ float cmin[WAVES][JSL];                        // 4 KiB

    // ---- stage 256 y-points: pack both k-half B fragments ----
    {
        const float* yp = y + ((size_t)b * N_ + (size_t)jg * JSL + t) * 3;
        const float f0 = yp[0], f1 = yp[1], f2 = yp[2];
        const unsigned short h0 = to_bf16(f0), h1 = to_bf16(f1), h2 = to_bf16(f2);
        const unsigned short l0 = to_bf16(f0 - from_bf16(h0));
        const unsigned short l1 = to_bf16(f1 - from_bf16(h1));
        const unsigned short l2 = to_bf16(f2 - from_bf16(h2));
        const float hy = 0.5f * (f0 * f0 + f1 * f1 + f2 * f2);
        const unsigned short hyh = to_bf16(hy);
        const unsigned short hyl = to_bf16(hy - from_bf16(hyh));
        unsigned short* p0 = &ldsB[0][t][0];
        p0[0] = h0; p0[1] = h1; p0[2] = h2;
        p0[3] = h0; p0[4] = h1; p0[5] = h2;
        p0[6] = l0; p0[7] = l1;
        unsigned short* p1 = &ldsB[1][t][0];
        p1[0] = l2; p1[1] = ONE; p1[2] = ONE;
        p1[3] = hyh; p1[4] = hyl;
        p1[5] = 0; p1[6] = 0; p1[7] = 0;
    }
    __syncthreads();

    float colp[JT];
    #pragma unroll
    for (int jt = 0; jt < JT; ++jt) colp[jt] = FLT_MAX;

    f32x16 zero;
    #pragma unroll
    for (int r = 0; r < 16; ++r) zero[r] = 0.0f;

    // ---- 4 i-tiles per wave, ONE live at a time (spill control) ----
    for (int k = 0; k < ITPW; ++k) {
        const int it = ig * (ISL / 32) + wv * ITPW + k;   // global i-tile

        // A fragment for this i-tile
        s16x8 af;
        {
            const float* xp = x + ((size_t)b * N_ + (size_t)it * 32 + lc) * 3;
            const float a0 = xp[0], a1 = xp[1], a2 = xp[2];
            const float n0 = -a0, n1 = -a1, n2 = -a2;
            const unsigned short xh0 = to_bf16(n0), xh1 = to_bf16(n1), xh2 = to_bf16(n2);
            const unsigned short xl0 = to_bf16(n0 - from_bf16(xh0));
            const unsigned short xl1 = to_bf16(n1 - from_bf16(xh1));
            const unsigned short xl2 = to_bf16(n2 - from_bf16(xh2));
            const float hx = 0.5f * (a0 * a0 + a1 * a1 + a2 * a2);
            const unsigned short hxh = to_bf16(hx);
            const unsigned short hxl = to_bf16(hx - from_bf16(hxh));
            if (hf == 0) {
                af[0] = (short)xh0; af[1] = (short)xh1; af[2] = (short)xh2;
                af[3] = (short)xl0; af[4] = (short)xl1; af[5] = (short)xl2;
                af[6] = (short)xh0; af[7] = (short)xh1;
            } else {
                af[0] = (short)xh2; af[1] = (short)hxh; af[2] = (short)hxl;
                af[3] = (short)ONE; af[4] = (short)ONE;
                af[5] = 0; af[6] = 0; af[7] = 0;
            }
        }

        float runmin[16];
        #pragma unroll
        for (int r = 0; r < 16; ++r) runmin[r] = FLT_MAX;

        #pragma unroll
        for (int jt = 0; jt < JT; ++jt) {
            const s16x8 bf = *(const s16x8*)&ldsB[hf][jt * 32 + lc][0];
            const f32x16 acc =
                __builtin_amdgcn_mfma_f32_32x32x16_bf16(af, bf, zero, 0, 0, 0);
            #pragma unroll
            for (int r = 0; r < 16; ++r)
                runmin[r] = fminf(runmin[r], acc[r]);
            const float c0 = fminf(fminf(acc[0], acc[1]),  fminf(acc[2], acc[3]));
            const float c1 = fminf(fminf(acc[4], acc[5]),  fminf(acc[6], acc[7]));
            const float c2 = fminf(fminf(acc[8], acc[9]),  fminf(acc[10], acc[11]));
            const float c3 = fminf(fminf(acc[12], acc[13]), fminf(acc[14], acc[15]));
            colp[jt] = fminf(colp[jt], fminf(fminf(c0, c1), fminf(c2, c3)));
        }

        // row-min across the 32 col-lanes (stays within each 32-lane half)
        #pragma unroll
        for (int r = 0; r < 16; ++r) {
            float v = runmin[r];
            v = fminf(v, __shfl_xor(v, 1, 64));
            v = fminf(v, __shfl_xor(v, 2, 64));
            v = fminf(v, __shfl_xor(v, 4, 64));
            v = fminf(v, __shfl_xor(v, 8, 64));
            v = fminf(v, __shfl_xor(v, 16, 64));
            runmin[r] = v;
        }
        if (lc == 0) {
            float* base = drow_part + ((size_t)jg * B_ + b) * N_
                        + (size_t)it * 32;
            #pragma unroll
            for (int r = 0; r < 16; ++r)
                base[(r & 3) + 8 * (r >> 2) + 4 * hf] = runmin[r];
        }
    }

    // ---- cols: combine halves + cross-wave via LDS, plain store ----
    #pragma unroll
    for (int jt = 0; jt < JT; ++jt) {
        float cw = colp[jt];
        cw = fminf(cw, __shfl_xor(cw, 32, 64));
        if (hf == 0) cmin[wv][jt * 32 + lc] = cw;
    }
    __syncthreads();
    {
        float m = cmin[0][t];
        #pragma unroll
        for (int w = 1; w < WAVES; ++w) m = fminf(m, cmin[w][t]);
        dcol_part[((size_t)ig * B_ + b) * N_ + (size_t)jg * JSL + t] = m;
    }
}

// out[b] = (2/N) * (sum_i min_jg drow_part[jg][b][i] + sum_j min_ig dcol_part[ig][b][j])
__global__ __launch_bounds__(THREADS)
void cd_sum_kernel(const float* __restrict__ drow_part,
                   const float* __restrict__ dcol_part,
                   float* __restrict__ out) {
    const int b = blockIdx.x;
    const int t = (int)threadIdx.x;

    float s = 0.0f;
    for (int i = t; i < N_; i += THREADS) {
        float m = drow_part[(size_t)b * N_ + i];
        #pragma unroll
        for (int jg = 1; jg < NJG; ++jg)
            m = fminf(m, drow_part[((size_t)jg * B_ + b) * N_ + i]);
        s += m;
    }
    for (int j = t; j < N_; j += THREADS) {
        float m = dcol_part[(size_t)b * N_ + j];
        #pragma unroll
        for (int ig = 1; ig < NIG; ++ig)
            m = fminf(m, dcol_part[((size_t)ig * B_ + b) * N_ + j]);
        s += m;
    }

    #pragma unroll
    for (int o = 32; o > 0; o >>= 1)
        s += __shfl_down(s, o, 64);

    __shared__ float red[THREADS / 64];
    if ((t & 63) == 0) red[t >> 6] = s;
    __syncthreads();
    if (t == 0) {
        float tot = 0.0f;
        #pragma unroll
        for (int w = 0; w < THREADS / 64; ++w) tot += red[w];
        out[b] = tot * (2.0f / (float)N_);
    }
}

extern "C" void kernel_launch(void* const* d_in, const int* in_sizes, int n_in,
                              void* d_out, int out_size, void* d_ws, size_t ws_size,
                              hipStream_t stream) {
    const float* x = (const float*)d_in[0];
    const float* y = (const float*)d_in[1];
    float* out       = (float*)d_out;
    float* drow_part = (float*)d_ws;                        // 1 MiB
    float* dcol_part = drow_part + (size_t)NJG * B_ * N_;   // 512 KiB

    cd_mfma_kernel<<<dim3(NJG, NIG, B_), dim3(THREADS), 0, stream>>>(
        x, y, drow_part, dcol_part);
    cd_sum_kernel<<<dim3(B_), dim3(THREADS), 0, stream>>>(
        drow_part, dcol_part, out);
}